// Round 2
// baseline (1091.991 us; speedup 1.0000x reference)
//
#include <hip/hip_runtime.h>
#include <hip/hip_bf16.h>

#define N_NODES 100000
#define N_EDGES 3200000
#define IN_CH   128
#define HID     32

// ---------------------------------------------------------------------------
// Detect whether edge_index is stored as int64 (odd 32-bit words all zero)
// or int32. flag[0] = 1 -> int64, 0 -> int32.
// ---------------------------------------------------------------------------
__global__ __launch_bounds__(256) void detect_idx(const int* __restrict__ ei,
                                                  int* __restrict__ flag) {
    __shared__ int nz;
    if (threadIdx.x == 0) nz = 0;
    __syncthreads();
    if (ei[2 * threadIdx.x + 1] != 0) atomicAdd(&nz, 1);
    __syncthreads();
    if (threadIdx.x == 0) flag[0] = (nz == 0) ? 1 : 0;
}

__device__ __forceinline__ int edge_at(const int* __restrict__ ei, int idx64,
                                       size_t pos) {
    if (idx64) return (int)((const long long*)ei)[pos];
    return ei[pos];
}

// ---------------------------------------------------------------------------
// Degree / normalization
// ---------------------------------------------------------------------------
__global__ __launch_bounds__(256) void init_deg(float* __restrict__ deg) {
    int i = blockIdx.x * 256 + threadIdx.x;
    if (i < N_NODES) deg[i] = 1.0f;   // self-loop contributes 1
}

__global__ __launch_bounds__(256) void count_deg(const int* __restrict__ ei,
                                                 const int* __restrict__ flag,
                                                 float* __restrict__ deg) {
    int i = blockIdx.x * 256 + threadIdx.x;
    if (i >= N_EDGES) return;
    int idx64 = flag[0];
    int d = edge_at(ei, idx64, (size_t)N_EDGES + i);   // dst = edge_index[1]
    atomicAdd(&deg[d], 1.0f);
}

__global__ __launch_bounds__(256) void make_dinv(float* __restrict__ deg) {
    int i = blockIdx.x * 256 + threadIdx.x;
    if (i < N_NODES) deg[i] = rsqrtf(deg[i]);   // deg >= 1 always
}

// ---------------------------------------------------------------------------
// GEMM1: h1s[n][c] = (sum_k x[n][k] * W1[k][c]) * dinv[n]
// block = 256 threads = 8 nodes x 32 channels; W1 staged in LDS.
// ---------------------------------------------------------------------------
__global__ __launch_bounds__(256) void gemm1_scale(
    const float* __restrict__ x,
    const float* __restrict__ W1,
    const float* __restrict__ dinv,
    float* __restrict__ h1s) {
    __shared__ float w[IN_CH * HID];   // 16 KB
    for (int i = threadIdx.x; i < IN_CH * HID; i += 256)
        w[i] = W1[i];
    __syncthreads();

    int node = blockIdx.x * 8 + (threadIdx.x >> 5);
    int c    = threadIdx.x & 31;
    if (node >= N_NODES) return;

    const float4* xr = reinterpret_cast<const float4*>(x + (size_t)node * IN_CH);
    float acc = 0.0f;
#pragma unroll
    for (int k4 = 0; k4 < IN_CH / 4; ++k4) {
        float4 v = xr[k4];
        acc += v.x * w[(k4 * 4 + 0) * HID + c]
             + v.y * w[(k4 * 4 + 1) * HID + c]
             + v.z * w[(k4 * 4 + 2) * HID + c]
             + v.w * w[(k4 * 4 + 3) * HID + c];
    }
    h1s[(size_t)node * HID + c] = acc * dinv[node];
}

// ---------------------------------------------------------------------------
// GEMM2: h3s[n][c] = (sum_k h2[n][k] * W2[k][c]) * dinv[n]
// ---------------------------------------------------------------------------
__global__ __launch_bounds__(256) void gemm2_scale(
    const float* __restrict__ h2,
    const float* __restrict__ W2,
    const float* __restrict__ dinv,
    float* __restrict__ h3s) {
    __shared__ float w[HID * HID];   // 4 KB
    for (int i = threadIdx.x; i < HID * HID; i += 256)
        w[i] = W2[i];
    __syncthreads();

    int node = blockIdx.x * 8 + (threadIdx.x >> 5);
    int c    = threadIdx.x & 31;
    if (node >= N_NODES) return;

    const float* hr = h2 + (size_t)node * HID;
    float acc = 0.0f;
#pragma unroll
    for (int k = 0; k < HID; ++k)
        acc += hr[k] * w[k * HID + c];
    h3s[(size_t)node * HID + c] = acc * dinv[node];
}

// ---------------------------------------------------------------------------
// Edge scatter: agg[dst][c] += hs[src][c]   (norm factored out entirely)
// one 32-lane group per edge; gathers 128B contiguous, atomics coalesced.
// ---------------------------------------------------------------------------
__global__ __launch_bounds__(256) void scatter_edges(
    const int* __restrict__ ei,
    const int* __restrict__ flag,
    const float* __restrict__ hs,
    float* __restrict__ agg) {
    int gid = blockIdx.x * 256 + threadIdx.x;     // E*32 = 102.4M < 2^31
    int e = gid >> 5;
    int c = gid & 31;
    if (e >= N_EDGES) return;
    int idx64 = flag[0];
    int s = edge_at(ei, idx64, (size_t)e);
    int d = edge_at(ei, idx64, (size_t)N_EDGES + e);
    atomicAdd(&agg[(size_t)d * HID + c], hs[(size_t)s * HID + c]);
}

// ---------------------------------------------------------------------------
// Epilogue 1: h2 = relu((agg + h1s) * dinv + b1)      [self-loop folded in]
// ---------------------------------------------------------------------------
__global__ __launch_bounds__(256) void epilogue1(
    const float* __restrict__ agg,
    const float* __restrict__ h1s,
    const float* __restrict__ dinv,
    const float* __restrict__ b1,
    float* __restrict__ h2) {
    int i = blockIdx.x * 256 + threadIdx.x;
    if (i >= N_NODES * HID) return;
    int n = i >> 5;
    int c = i & 31;
    float v = (agg[i] + h1s[i]) * dinv[n] + b1[c];
    h2[i] = v > 0.0f ? v : 0.0f;
}

// ---------------------------------------------------------------------------
// Epilogue 2: out = (agg + h3s) * dinv + b2   (f32 out, no relu)
// ---------------------------------------------------------------------------
__global__ __launch_bounds__(256) void epilogue2(
    const float* __restrict__ agg,
    const float* __restrict__ h3s,
    const float* __restrict__ dinv,
    const float* __restrict__ b2,
    float* __restrict__ out) {
    int i = blockIdx.x * 256 + threadIdx.x;
    if (i >= N_NODES * HID) return;
    int n = i >> 5;
    int c = i & 31;
    out[i] = (agg[i] + h3s[i]) * dinv[n] + b2[c];
}

// ---------------------------------------------------------------------------
extern "C" void kernel_launch(void* const* d_in, const int* in_sizes, int n_in,
                              void* d_out, int out_size, void* d_ws, size_t ws_size,
                              hipStream_t stream) {
    const float* x  = (const float*)d_in[0];
    const int*   ei = (const int*)d_in[1];
    const float* W1 = (const float*)d_in[2];
    const float* b1 = (const float*)d_in[3];
    const float* W2 = (const float*)d_in[4];
    const float* b2 = (const float*)d_in[5];
    float* out = (float*)d_out;

    // workspace layout: flag (256B) | dinv[N] | bufA[N*32] | agg[N*32] | h2[N*32]
    int*   flag = (int*)d_ws;
    float* dinv = (float*)d_ws + 64;
    float* bufA = dinv + N_NODES;
    float* agg  = bufA + (size_t)N_NODES * HID;
    float* h2   = agg  + (size_t)N_NODES * HID;

    const int nodeBlocks = (N_NODES + 255) / 256;                       // 391
    const int gemmBlocks = (N_NODES + 7) / 8;                           // 12500
    const int edgeBlocks = (N_EDGES + 255) / 256;                       // 12500
    const int scatBlocks = (int)(((size_t)N_EDGES * HID + 255) / 256);  // 400000
    const int elemBlocks = (N_NODES * HID + 255) / 256;                 // 12500

    detect_idx<<<1, 256, 0, stream>>>(ei, flag);

    // normalization
    init_deg<<<nodeBlocks, 256, 0, stream>>>(dinv);
    count_deg<<<edgeBlocks, 256, 0, stream>>>(ei, flag, dinv);
    make_dinv<<<nodeBlocks, 256, 0, stream>>>(dinv);

    // layer 1
    gemm1_scale<<<gemmBlocks, 256, 0, stream>>>(x, W1, dinv, bufA);
    hipMemsetAsync(agg, 0, (size_t)N_NODES * HID * sizeof(float), stream);
    scatter_edges<<<scatBlocks, 256, 0, stream>>>(ei, flag, bufA, agg);
    epilogue1<<<elemBlocks, 256, 0, stream>>>(agg, bufA, dinv, b1, h2);

    // layer 2
    gemm2_scale<<<gemmBlocks, 256, 0, stream>>>(h2, W2, dinv, bufA);
    hipMemsetAsync(agg, 0, (size_t)N_NODES * HID * sizeof(float), stream);
    scatter_edges<<<scatBlocks, 256, 0, stream>>>(ei, flag, bufA, agg);
    epilogue2<<<elemBlocks, 256, 0, stream>>>(agg, bufA, dinv, b2, out);
}

// Round 3
// 769.328 us; speedup vs baseline: 1.4194x; 1.4194x over previous
//
#include <hip/hip_runtime.h>
#include <hip/hip_bf16.h>

#define N_NODES 100000
#define N_EDGES 3200000
#define IN_CH   128
#define HID     32

// ---------------------------------------------------------------------------
// Detect whether edge_index is int64 (odd 32-bit words all zero) or int32.
// flag[0] = 1 -> int64, 0 -> int32.
// ---------------------------------------------------------------------------
__global__ __launch_bounds__(256) void detect_idx(const int* __restrict__ ei,
                                                  int* __restrict__ flag) {
    __shared__ int nz;
    if (threadIdx.x == 0) nz = 0;
    __syncthreads();
    if (ei[2 * threadIdx.x + 1] != 0) atomicAdd(&nz, 1);
    __syncthreads();
    if (threadIdx.x == 0) flag[0] = (nz == 0) ? 1 : 0;
}

__device__ __forceinline__ int edge_at(const int* __restrict__ ei, int idx64,
                                       size_t pos) {
    if (idx64) return (int)((const long long*)ei)[pos];
    return ei[pos];
}

// ---------------------------------------------------------------------------
// Degree / CSR build
// ---------------------------------------------------------------------------
__global__ __launch_bounds__(256) void zero_deg(int* __restrict__ deg) {
    int i = blockIdx.x * 256 + threadIdx.x;
    if (i < N_NODES) deg[i] = 0;
}

__global__ __launch_bounds__(256) void count_deg(const int* __restrict__ ei,
                                                 const int* __restrict__ flag,
                                                 int* __restrict__ deg) {
    int i = blockIdx.x * 256 + threadIdx.x;
    if (i >= N_EDGES) return;
    int idx64 = flag[0];
    int d = edge_at(ei, idx64, (size_t)N_EDGES + i);   // dst = edge_index[1]
    atomicAdd(&deg[d], 1);
}

__global__ __launch_bounds__(256) void make_dinv(const int* __restrict__ deg,
                                                 float* __restrict__ dinv) {
    int i = blockIdx.x * 256 + threadIdx.x;
    if (i < N_NODES) dinv[i] = rsqrtf((float)(deg[i] + 1));  // +1 self-loop
}

// --- exclusive scan of deg -> rowptr (3 kernels) ---------------------------
// s1: per-block (1024 elems) exclusive scan into rowptr, block sums -> partials
__global__ __launch_bounds__(256) void scan_s1(const int* __restrict__ deg,
                                               int* __restrict__ rowptr,
                                               int* __restrict__ partials) {
    __shared__ int tmp[256];
    int t = threadIdx.x;
    int base = blockIdx.x * 1024;
    int v[4];
#pragma unroll
    for (int j = 0; j < 4; ++j) {
        int idx = base + t * 4 + j;
        v[j] = (idx < N_NODES) ? deg[idx] : 0;
    }
    int s = v[0] + v[1] + v[2] + v[3];
    tmp[t] = s;
    __syncthreads();
    for (int off = 1; off < 256; off <<= 1) {
        int x = 0;
        if (t >= off) x = tmp[t - off];
        __syncthreads();
        if (t >= off) tmp[t] += x;
        __syncthreads();
    }
    int run = tmp[t] - s;   // exclusive prefix of this thread's chunk
#pragma unroll
    for (int j = 0; j < 4; ++j) {
        int idx = base + t * 4 + j;
        if (idx < N_NODES) rowptr[idx] = run;
        run += v[j];
    }
    if (t == 255) partials[blockIdx.x] = tmp[255];
}

// s2: exclusive scan of the 98 block sums (single block)
__global__ __launch_bounds__(128) void scan_s2(int* __restrict__ partials) {
    __shared__ int tmp[128];
    int t = threadIdx.x;
    int v = (t < 98) ? partials[t] : 0;
    tmp[t] = v;
    __syncthreads();
    for (int off = 1; off < 128; off <<= 1) {
        int x = 0;
        if (t >= off) x = tmp[t - off];
        __syncthreads();
        if (t >= off) tmp[t] += x;
        __syncthreads();
    }
    if (t < 98) partials[t] = tmp[t] - v;
}

// s3: add block offsets in place; copy to cursor; write rowptr[N]
__global__ __launch_bounds__(256) void scan_s3(int* __restrict__ rowptr,
                                               const int* __restrict__ partials,
                                               int* __restrict__ cursor) {
    int i = blockIdx.x * 256 + threadIdx.x;
    if (i < N_NODES) {
        int r = rowptr[i] + partials[i >> 10];
        rowptr[i] = r;
        cursor[i] = r;
    }
    if (i == N_NODES) rowptr[N_NODES] = N_EDGES;
}

__global__ __launch_bounds__(256) void fill_csr(const int* __restrict__ ei,
                                                const int* __restrict__ flag,
                                                int* __restrict__ cursor,
                                                int* __restrict__ col) {
    int i = blockIdx.x * 256 + threadIdx.x;
    if (i >= N_EDGES) return;
    int idx64 = flag[0];
    int s = edge_at(ei, idx64, (size_t)i);
    int d = edge_at(ei, idx64, (size_t)N_EDGES + i);
    int pos = atomicAdd(&cursor[d], 1);
    col[pos] = s;
}

// ---------------------------------------------------------------------------
// GEMM1: h1s[n][c] = (sum_k x[n][k] * W1[k][c]) * dinv[n]
// ---------------------------------------------------------------------------
__global__ __launch_bounds__(256) void gemm1_scale(
    const float* __restrict__ x,
    const float* __restrict__ W1,
    const float* __restrict__ dinv,
    float* __restrict__ h1s) {
    __shared__ float w[IN_CH * HID];   // 16 KB
    for (int i = threadIdx.x; i < IN_CH * HID; i += 256)
        w[i] = W1[i];
    __syncthreads();

    int node = blockIdx.x * 8 + (threadIdx.x >> 5);
    int c    = threadIdx.x & 31;
    if (node >= N_NODES) return;

    const float4* xr = reinterpret_cast<const float4*>(x + (size_t)node * IN_CH);
    float acc = 0.0f;
#pragma unroll
    for (int k4 = 0; k4 < IN_CH / 4; ++k4) {
        float4 v = xr[k4];
        acc += v.x * w[(k4 * 4 + 0) * HID + c]
             + v.y * w[(k4 * 4 + 1) * HID + c]
             + v.z * w[(k4 * 4 + 2) * HID + c]
             + v.w * w[(k4 * 4 + 3) * HID + c];
    }
    h1s[(size_t)node * HID + c] = acc * dinv[node];
}

// ---------------------------------------------------------------------------
// Layer-1 aggregate, fused: gather-sum h1s over in-edges + self, epilogue1
// (relu), then gemm2 via lane shuffles, scale by dinv -> h3s.
// 32 lanes per node (lane = channel), 8 nodes per 256-thread block.
// ---------------------------------------------------------------------------
__global__ __launch_bounds__(256) void aggregate1(
    const int* __restrict__ rowptr,
    const int* __restrict__ col,
    const float* __restrict__ h1s,
    const float* __restrict__ dinv,
    const float* __restrict__ b1,
    const float* __restrict__ W2,
    float* __restrict__ h3s) {
    __shared__ float w2s[HID * HID];   // 4 KB
    for (int i = threadIdx.x; i < HID * HID; i += 256)
        w2s[i] = W2[i];
    __syncthreads();

    int node = blockIdx.x * 8 + (threadIdx.x >> 5);
    int c    = threadIdx.x & 31;
    if (node >= N_NODES) return;

    int e0 = rowptr[node];
    int e1 = rowptr[node + 1];
    float a0 = h1s[(size_t)node * HID + c];  // self-loop (pre-scaled by dinv[n])
    float a1 = 0.f, a2 = 0.f, a3 = 0.f;
    int e = e0;
    for (; e + 4 <= e1; e += 4) {
        int s0 = col[e], s1 = col[e + 1], s2 = col[e + 2], s3 = col[e + 3];
        a0 += h1s[(size_t)s0 * HID + c];
        a1 += h1s[(size_t)s1 * HID + c];
        a2 += h1s[(size_t)s2 * HID + c];
        a3 += h1s[(size_t)s3 * HID + c];
    }
    for (; e < e1; ++e)
        a1 += h1s[(size_t)col[e] * HID + c];

    float dn = dinv[node];
    float h2v = ((a0 + a1) + (a2 + a3)) * dn + b1[c];
    h2v = h2v > 0.0f ? h2v : 0.0f;

    // gemm2: h3[c] = sum_k h2[k] * W2[k][c]  (h2 row lives across the 32 lanes)
    float acc2 = 0.0f;
#pragma unroll
    for (int k = 0; k < HID; ++k)
        acc2 += __shfl(h2v, k, 32) * w2s[k * HID + c];

    h3s[(size_t)node * HID + c] = acc2 * dn;
}

// ---------------------------------------------------------------------------
// Layer-2 aggregate, fused epilogue2: out = (gather-sum h3s + self)*dinv + b2
// ---------------------------------------------------------------------------
__global__ __launch_bounds__(256) void aggregate2(
    const int* __restrict__ rowptr,
    const int* __restrict__ col,
    const float* __restrict__ h3s,
    const float* __restrict__ dinv,
    const float* __restrict__ b2,
    float* __restrict__ out) {
    int node = blockIdx.x * 8 + (threadIdx.x >> 5);
    int c    = threadIdx.x & 31;
    if (node >= N_NODES) return;

    int e0 = rowptr[node];
    int e1 = rowptr[node + 1];
    float a0 = h3s[(size_t)node * HID + c];  // self-loop
    float a1 = 0.f, a2 = 0.f, a3 = 0.f;
    int e = e0;
    for (; e + 4 <= e1; e += 4) {
        int s0 = col[e], s1 = col[e + 1], s2 = col[e + 2], s3 = col[e + 3];
        a0 += h3s[(size_t)s0 * HID + c];
        a1 += h3s[(size_t)s1 * HID + c];
        a2 += h3s[(size_t)s2 * HID + c];
        a3 += h3s[(size_t)s3 * HID + c];
    }
    for (; e < e1; ++e)
        a1 += h3s[(size_t)col[e] * HID + c];

    out[(size_t)node * HID + c] = ((a0 + a1) + (a2 + a3)) * dinv[node] + b2[c];
}

// ---------------------------------------------------------------------------
extern "C" void kernel_launch(void* const* d_in, const int* in_sizes, int n_in,
                              void* d_out, int out_size, void* d_ws, size_t ws_size,
                              hipStream_t stream) {
    const float* x  = (const float*)d_in[0];
    const int*   ei = (const int*)d_in[1];
    const float* W1 = (const float*)d_in[2];
    const float* b1 = (const float*)d_in[3];
    const float* W2 = (const float*)d_in[4];
    const float* b2 = (const float*)d_in[5];
    float* out = (float*)d_out;

    // workspace layout:
    // flag[64] | deg[N] (reused as cursor) | rowptr[N+1] | partials[128] |
    // col[E] | dinv[N] | h1s[N*32] | h3s[N*32]     (~37.8 MiB total)
    int*   flag     = (int*)d_ws;
    int*   deg      = flag + 64;                    // also the CSR cursor
    int*   rowptr   = deg + N_NODES;
    int*   partials = rowptr + (N_NODES + 1);
    int*   col      = partials + 128;
    float* dinv     = (float*)(col + N_EDGES);
    float* h1s      = dinv + N_NODES;
    float* h3s      = h1s + (size_t)N_NODES * HID;

    const int nodeBlocks = (N_NODES + 255) / 256;        // 391
    const int node1Blocks = (N_NODES + 256) / 256;       // 392 (covers i==N)
    const int gemmBlocks = (N_NODES + 7) / 8;            // 12500
    const int edgeBlocks = (N_EDGES + 255) / 256;        // 12500
    const int scanBlocks = (N_NODES + 1023) / 1024;      // 98

    detect_idx<<<1, 256, 0, stream>>>(ei, flag);

    // CSR build + normalization
    zero_deg<<<nodeBlocks, 256, 0, stream>>>(deg);
    count_deg<<<edgeBlocks, 256, 0, stream>>>(ei, flag, deg);
    make_dinv<<<nodeBlocks, 256, 0, stream>>>(deg, dinv);
    scan_s1<<<scanBlocks, 256, 0, stream>>>(deg, rowptr, partials);
    scan_s2<<<1, 128, 0, stream>>>(partials);
    scan_s3<<<node1Blocks, 256, 0, stream>>>(rowptr, partials, deg /*cursor*/);
    fill_csr<<<edgeBlocks, 256, 0, stream>>>(ei, flag, deg /*cursor*/, col);

    // layer 1 (+ fused relu + gemm2)
    gemm1_scale<<<gemmBlocks, 256, 0, stream>>>(x, W1, dinv, h1s);
    aggregate1<<<gemmBlocks, 256, 0, stream>>>(rowptr, col, h1s, dinv, b1, W2, h3s);

    // layer 2 (+ fused epilogue)
    aggregate2<<<gemmBlocks, 256, 0, stream>>>(rowptr, col, h3s, dinv, b2, out);
}